// Round 6
// baseline (161.386 us; speedup 1.0000x reference)
//
#include <hip/hip_runtime.h>
#include <hip/hip_bf16.h>
#include <math.h>

#define GN 1024
#define GM 32
#define GD 512
#define NROW (GN*GM)   // 32768

// ---------------- ws layout (bytes) ----------------
#define WS_XB    0ull                  // bf16 [NROW][GD]  = 33554432 B
#define WS_SB    33554432ull           // bf16 [GN][GD]    =  1048576 B
#define WS_INVSN 34603008ull           // f32  [GN]        =     4096 B
#define WS_INVXN 34607104ull           // f32  [NROW]      =   131072 B
#define WS_CSOWN 34738176ull           // f32  [NROW]      =   131072 B
#define WS_PS    34869248ull           // f32  [NROW*16]   =  2097152 B

typedef __attribute__((ext_vector_type(8))) short bf16x8;
typedef __attribute__((ext_vector_type(4))) float f32x4;

// ---------------------------------------------------------------------------
// Kernel A: per speaker n — centroid sums, norms, own-centroid cosine,
// plus bf16 conversion of x and S for the MFMA GEMM.
// grid GN blocks, 512 threads.
// ---------------------------------------------------------------------------
__global__ __launch_bounds__(512) void prep_kernel(
    const float* __restrict__ x, const float* __restrict__ wp,
    const float* __restrict__ bp, char* __restrict__ wsb)
{
    __hip_bfloat16* xbw  = (__hip_bfloat16*)(wsb + WS_XB);
    __hip_bfloat16* Sbw  = (__hip_bfloat16*)(wsb + WS_SB);
    float* invSn = (float*)(wsb + WS_INVSN);
    float* invxn = (float*)(wsb + WS_INVXN);
    float* csown = (float*)(wsb + WS_CSOWN);

    const int n = blockIdx.x;
    const int d = threadIdx.x;           // 0..511
    const int lane = threadIdx.x & 63;
    const int wid  = threadIdx.x >> 6;   // 0..7

    __shared__ float sS[GD];
    __shared__ float red[8];
    __shared__ float sSn2;

    const float* xn_ = x + (size_t)n * GM * GD;

    // phase 1: column sums S[n,d] + bf16 conversion of x
    float Sd = 0.f;
    #pragma unroll
    for (int m = 0; m < GM; ++m) {
        float xv = xn_[m * GD + d];
        Sd += xv;
        xbw[(size_t)(n * GM + m) * GD + d] = __float2bfloat16(xv);
    }
    sS[d] = Sd;
    Sbw[(size_t)n * GD + d] = __float2bfloat16(Sd);

    // block reduce Sd^2 -> ||S||^2
    float p = Sd * Sd;
    #pragma unroll
    for (int off = 32; off > 0; off >>= 1) p += __shfl_down(p, off);
    if (lane == 0) red[wid] = p;
    __syncthreads();
    if (threadIdx.x == 0) {
        float s = 0.f;
        #pragma unroll
        for (int i = 0; i < 8; ++i) s += red[i];
        sSn2 = s;
        invSn[n] = rsqrtf(s);
    }
    __syncthreads();

    // phase 2: per-utterance norms + dot(x, S)
    const float w0 = wp[0], b0 = bp[0];
    const float Sn2 = sSn2;
    #pragma unroll
    for (int mm = 0; mm < 4; ++mm) {
        const int m = wid + mm * 8;
        float xn2 = 0.f, dn = 0.f;
        #pragma unroll
        for (int j = 0; j < 8; ++j) {
            float xv = xn_[m * GD + lane + 64 * j];
            float sv = sS[lane + 64 * j];
            xn2 += xv * xv;
            dn  += xv * sv;
        }
        #pragma unroll
        for (int off = 32; off > 0; off >>= 1) {
            xn2 += __shfl_down(xn2, off);
            dn  += __shfl_down(dn, off);
        }
        if (lane == 0) {
            float ixn = rsqrtf(xn2);
            float en2 = Sn2 - 2.f * dn + xn2;          // ||S - x||^2
            float cosown = (dn - xn2) * ixn * rsqrtf(en2);
            csown[n * GM + m] = w0 * fmaxf(cosown, 1e-6f) + b0;
            invxn[n * GM + m] = ixn;
        }
    }
}

// ---------------------------------------------------------------------------
// Kernel B: bf16 MFMA GEMM G = xb(32768x512) * Sb^T(512x1024).
// 128x128 tile / 4 waves (2x2) / 4x4 16x16x32 fragments per wave.
// NO LDS, NO barriers: every lane loads its MFMA fragments directly
// global->VGPR (16-B dwordx4; a wave covers 16 full cache lines per
// fragment). Operands are L2/L3-resident (B = 1 MB total; A-panels via
// XCD swizzle), wr/wc duplicate fetches hit L1/L2. The K loop is a flat
// dataflow graph the compiler pipelines freely. Fused fixed-shift
// partial-softmax epilogue. grid 2048 blocks, 256 threads.
// ---------------------------------------------------------------------------
__global__ __launch_bounds__(256) void gemm_kernel(
    const float* __restrict__ wp, const float* __restrict__ bp,
    char* __restrict__ wsb)
{
    const __hip_bfloat16* xb  = (const __hip_bfloat16*)(wsb + WS_XB);
    const __hip_bfloat16* Sbm = (const __hip_bfloat16*)(wsb + WS_SB);
    const float* invSn = (const float*)(wsb + WS_INVSN);
    const float* invxn = (const float*)(wsb + WS_INVXN);
    const float* csown = (const float*)(wsb + WS_CSOWN);
    float* ps = (float*)(wsb + WS_PS);

    // XCD swizzle: hw xcd = bid & 7 owns row-panels [xcd*32, xcd*32+32),
    // walking col-panels fastest.
    const int bid  = blockIdx.x;          // 0..2047
    const int u    = bid >> 3;            // 0..255
    const int rowp = (bid & 7) * 32 + (u >> 3);
    const int colp = u & 7;
    const int rbase = rowp * 128;
    const int cbase = colp * 128;

    const int t    = threadIdx.x;
    const int w    = t >> 6;
    const int lane = t & 63;
    const int wr   = w >> 1, wc = w & 1;

    const int kb  = lane >> 4;   // k-chunk 0..3 within 32-k step (also C row-group)
    const int r16 = lane & 15;

    f32x4 acc[4][4] = {};

    // per-lane fragment base pointers; k-step advances by 32 elems = 64 B,
    // folded into the load immediate offset by the unrolled loop.
    const __hip_bfloat16* aptr[4];
    const __hip_bfloat16* bptr[4];
    #pragma unroll
    for (int mi = 0; mi < 4; ++mi)
        aptr[mi] = xb + (size_t)(rbase + wr * 64 + mi * 16 + r16) * GD + kb * 8;
    #pragma unroll
    for (int nj = 0; nj < 4; ++nj)
        bptr[nj] = Sbm + (size_t)(cbase + wc * 64 + nj * 16 + r16) * GD + kb * 8;

    #pragma unroll
    for (int ks = 0; ks < 16; ++ks) {
        bf16x8 af[4], bfr[4];
        #pragma unroll
        for (int mi = 0; mi < 4; ++mi)
            af[mi] = *(const bf16x8*)(aptr[mi] + ks * 32);
        #pragma unroll
        for (int nj = 0; nj < 4; ++nj)
            bfr[nj] = *(const bf16x8*)(bptr[nj] + ks * 32);
        #pragma unroll
        for (int mi = 0; mi < 4; ++mi)
            #pragma unroll
            for (int nj = 0; nj < 4; ++nj)
                acc[mi][nj] = __builtin_amdgcn_mfma_f32_16x16x32_bf16(
                    af[mi], bfr[nj], acc[mi][nj], 0, 0, 0);
    }

    // ---- fused epilogue: fixed-shift partial softmax over 64-col wave tile
    const float w0 = wp[0], b0 = bp[0];
    const float C = fmaxf(w0 * 1e-6f + b0, w0 + b0);   // logit upper bound
    const int pcol = colp * 2 + wc;                    // 0..15 partial slot
    float isn[4];
    #pragma unroll
    for (int nj = 0; nj < 4; ++nj)
        isn[nj] = invSn[cbase + wc * 64 + nj * 16 + r16];

    #pragma unroll
    for (int mi = 0; mi < 4; ++mi) {
        #pragma unroll
        for (int r = 0; r < 4; ++r) {
            const int row = rbase + wr * 64 + mi * 16 + kb * 4 + r;
            const float ixn = invxn[row];
            const float cso = csown[row];
            const int own = row >> 5;
            float se = 0.f;
            #pragma unroll
            for (int nj = 0; nj < 4; ++nj) {
                const int col = cbase + wc * 64 + nj * 16 + r16;
                float cs = w0 * fmaxf(acc[mi][nj][r] * ixn * isn[nj], 1e-6f) + b0;
                cs = (col == own) ? cso : cs;
                se += __expf(cs - C);
            }
            #pragma unroll
            for (int off = 1; off < 16; off <<= 1)
                se += __shfl_xor(se, off, 16);
            if (r16 == 0)
                ps[(size_t)row * 16 + pcol] = se;
        }
    }
}

// ---------------------------------------------------------------------------
// Kernel C: combine 16 sum-partials per row (shared fixed shift C),
// loss = C + log(sum) - cs_own, mean-reduce into d_out[0].
// ---------------------------------------------------------------------------
__global__ __launch_bounds__(256) void finalize_kernel(
    const char* __restrict__ wsb, const float* __restrict__ wp,
    const float* __restrict__ bp, float* __restrict__ out)
{
    const float* csown = (const float*)(wsb + WS_CSOWN);
    const float* ps    = (const float*)(wsb + WS_PS);

    const float w0 = wp[0], b0 = bp[0];
    const float C = fmaxf(w0 * 1e-6f + b0, w0 + b0);

    const int row = blockIdx.x * 256 + threadIdx.x;
    float s = 0.f;
    #pragma unroll
    for (int i = 0; i < 16; ++i) s += ps[(size_t)row * 16 + i];
    float loss = C + logf(s) - csown[row];

    const int lane = threadIdx.x & 63;
    const int wid  = threadIdx.x >> 6;
    __shared__ float red[4];
    #pragma unroll
    for (int off = 32; off > 0; off >>= 1) loss += __shfl_down(loss, off);
    if (lane == 0) red[wid] = loss;
    __syncthreads();
    if (threadIdx.x == 0) {
        float sum = red[0] + red[1] + red[2] + red[3];
        atomicAdd(out, sum * (1.f / (GN * GM)));
    }
}

extern "C" void kernel_launch(void* const* d_in, const int* in_sizes, int n_in,
                              void* d_out, int out_size, void* d_ws, size_t ws_size,
                              hipStream_t stream)
{
    const float* x  = (const float*)d_in[0];
    const float* wp = (const float*)d_in[1];
    const float* bp = (const float*)d_in[2];
    float* out = (float*)d_out;
    char* wsb  = (char*)d_ws;

    hipMemsetAsync(d_out, 0, sizeof(float), stream);

    prep_kernel<<<GN, 512, 0, stream>>>(x, wp, bp, wsb);

    gemm_kernel<<<2048, 256, 0, stream>>>(wp, bp, wsb);

    finalize_kernel<<<128, 256, 0, stream>>>(wsb, wp, bp, out);
}

// Round 7
// 107.947 us; speedup vs baseline: 1.4951x; 1.4951x over previous
//
#include <hip/hip_runtime.h>
#include <hip/hip_bf16.h>
#include <hip/hip_fp8.h>
#include <math.h>

#define GN 1024
#define GM 32
#define GD 512
#define NROW (GN*GM)   // 32768

// ---------------- ws layout (bytes) ----------------
#define WS_XF8   0ull                  // u8 [NROW][512] = 16777216 (permuted fp8 image)
#define WS_SF8   16777216ull           // u8 [GN][512]   =   524288
#define WS_INVSN 17301504ull           // f32 [GN]
#define WS_INVXN 17305600ull           // f32 [NROW]
#define WS_CSOWN 17436672ull           // f32 [NROW]
#define WS_PS    17567744ull           // f32 [NROW*16]

typedef __attribute__((ext_vector_type(2))) long i64x2;
typedef __attribute__((ext_vector_type(4))) float f32x4;

__device__ inline unsigned char f32_to_e4m3(float f) {
    __hip_fp8_e4m3 q(f);               // OCP e4m3fn, saturating
    return (unsigned char)q.__x;
}

// fp8 image permutation within each row's 512 bytes:
// slot (ks, kb) 16B = [ksub0: k=ks*64+kb*8+j | ksub1: k=ks*64+32+kb*8+j]
// off(k) = (k & ~63) + ((k>>3)&3)*16 + ((k>>5)&1)*8 + (k&7)
__device__ inline int img_off(int k) {
    const int rem = k & 63;
    return (k & ~63) + ((rem >> 3) & 3) * 16 + (rem >> 5) * 8 + (rem & 7);
}

// ---------------------------------------------------------------------------
// Kernel A: per speaker n — centroid sums, norms, own-centroid cosine,
// plus permuted-fp8 conversion of x and S. x read ONCE (carried in regs).
// grid GN blocks, 512 threads.
// ---------------------------------------------------------------------------
__global__ __launch_bounds__(512) void prep_kernel(
    const float* __restrict__ x, const float* __restrict__ wp,
    const float* __restrict__ bp, char* __restrict__ wsb)
{
    unsigned char* xf8 = (unsigned char*)(wsb + WS_XF8);
    unsigned char* Sf8 = (unsigned char*)(wsb + WS_SF8);
    float* invSn = (float*)(wsb + WS_INVSN);
    float* invxn = (float*)(wsb + WS_INVXN);
    float* csown = (float*)(wsb + WS_CSOWN);

    const int n = blockIdx.x;
    const int d = threadIdx.x;           // 0..511 (= k index)
    const int lane = d & 63;
    const int wid  = d >> 6;             // 0..7

    __shared__ float red[8];
    __shared__ float2 red2[8][GM];

    const float* xn_ = x + (size_t)n * GM * GD;
    const int off = img_off(d);

    // load x once, keep in registers; column sum S[d]
    float xv[GM];
    float Sd = 0.f;
    #pragma unroll
    for (int m = 0; m < GM; ++m) {
        xv[m] = xn_[m * GD + d];
        Sd += xv[m];
    }
    // fp8 image stores (each wave permutes within 64-B windows -> coalesced)
    #pragma unroll
    for (int m = 0; m < GM; ++m)
        xf8[(size_t)(n * GM + m) * GD + off] = f32_to_e4m3(xv[m]);
    Sf8[(size_t)n * GD + off] = f32_to_e4m3(Sd);

    // ||S||^2 partials
    float p = Sd * Sd;
    #pragma unroll
    for (int o = 32; o > 0; o >>= 1) p += __shfl_down(p, o);
    if (lane == 0) red[wid] = p;

    // per-m partials: ||x_m||^2 and dot(x_m, S)
    #pragma unroll
    for (int m = 0; m < GM; ++m) {
        float a = xv[m] * xv[m];
        float b = xv[m] * Sd;
        #pragma unroll
        for (int o = 32; o > 0; o >>= 1) {
            a += __shfl_down(a, o);
            b += __shfl_down(b, o);
        }
        if (lane == 0) red2[wid][m] = make_float2(a, b);
    }
    __syncthreads();

    if (d < GM) {                        // thread d handles utterance m=d
        float Sn2 = 0.f;
        #pragma unroll
        for (int i = 0; i < 8; ++i) Sn2 += red[i];
        if (d == 0) invSn[n] = rsqrtf(Sn2);

        float xn2 = 0.f, dn = 0.f;
        #pragma unroll
        for (int i = 0; i < 8; ++i) {
            xn2 += red2[i][d].x;
            dn  += red2[i][d].y;
        }
        const float w0 = wp[0], b0 = bp[0];
        float ixn = rsqrtf(xn2);
        float en2 = Sn2 - 2.f * dn + xn2;              // ||S - x||^2
        float cosown = (dn - xn2) * ixn * rsqrtf(en2);
        csown[n * GM + d] = w0 * fmaxf(cosown, 1e-6f) + b0;
        invxn[n * GM + d] = ixn;
    }
}

// ---------------------------------------------------------------------------
// Kernel B: fp8 MFMA GEMM G = x(32768x512) * S^T(512x1024), e4m3 inputs.
// 128x128 tile / BK=64 / 4 waves (2x2) / 4x4 fragments, 2 k-sub MFMAs per
// ds_read_b128 (mfma_f32_16x16x32_fp8_fp8). 3 LDS buffers (48 KB -> 3
// blocks/CU), prefetch distance 2, ONE raw s_barrier per K-step, counted
// vmcnt(4). 8 K-steps. XCD-aware bid swizzle. Fused fixed-shift
// partial-softmax epilogue. grid 2048 blocks, 256 threads.
// ---------------------------------------------------------------------------
__global__ __launch_bounds__(256) void gemm_kernel(
    const float* __restrict__ wp, const float* __restrict__ bp,
    char* __restrict__ wsb)
{
    const unsigned char* xf8 = (const unsigned char*)(wsb + WS_XF8);
    const unsigned char* Sf8 = (const unsigned char*)(wsb + WS_SF8);
    const float* invSn = (const float*)(wsb + WS_INVSN);
    const float* invxn = (const float*)(wsb + WS_INVXN);
    const float* csown = (const float*)(wsb + WS_CSOWN);
    float* ps = (float*)(wsb + WS_PS);

    // slot s = kb*128 + row; 16 B = both k-subs of (row, kb) for this step
    __shared__ __align__(16) unsigned char Ab[3][512][16];
    __shared__ __align__(16) unsigned char Bb[3][512][16];

    // XCD swizzle: hw xcd = bid & 7 owns row-panels [xcd*32, xcd*32+32)
    const int bid  = blockIdx.x;          // 0..2047
    const int u    = bid >> 3;            // 0..255
    const int rowp = (bid & 7) * 32 + (u >> 3);
    const int colp = u & 7;
    const int rbase = rowp * 128;
    const int cbase = colp * 128;

    const int t    = threadIdx.x;
    const int w    = t >> 6;
    const int lane = t & 63;
    const int wr   = w >> 1, wc = w & 1;

    const int kb  = lane >> 4;   // k-chunk 0..3 (also C row-group)
    const int r16 = lane & 15;

    f32x4 acc[4][4] = {};

    // staging slots for this thread: s = p*256 + t, p = 0..1
    const int s0 = t, s1 = 256 + t;
    const int arow0 = rbase + (s0 & 127), akq0 = (s0 >> 7) * 16;
    const int arow1 = rbase + (s1 & 127), akq1 = (s1 >> 7) * 16;
    const int brow0 = cbase + (s0 & 127);
    const int brow1 = cbase + (s1 & 127);
    // wave-uniform LDS slot bases (HW adds lane*16B)
    const int base0 = (t >> 6) * 64;          // slots   0..255 region
    const int base1 = 256 + (t >> 6) * 64;    // slots 256..511 region

#define STAGE(buf, ks)                                                        \
    do {                                                                      \
        const int kof_ = (ks) * 64;                                           \
        __builtin_amdgcn_global_load_lds(                                     \
            (const __attribute__((address_space(1))) void*)(xf8 +             \
                (size_t)arow0 * GD + kof_ + akq0),                            \
            (__attribute__((address_space(3))) void*)&Ab[buf][base0][0],      \
            16, 0, 0);                                                        \
        __builtin_amdgcn_global_load_lds(                                     \
            (const __attribute__((address_space(1))) void*)(xf8 +             \
                (size_t)arow1 * GD + kof_ + akq1),                            \
            (__attribute__((address_space(3))) void*)&Ab[buf][base1][0],      \
            16, 0, 0);                                                        \
        __builtin_amdgcn_global_load_lds(                                     \
            (const __attribute__((address_space(1))) void*)(Sf8 +             \
                (size_t)brow0 * GD + kof_ + akq0),                            \
            (__attribute__((address_space(3))) void*)&Bb[buf][base0][0],      \
            16, 0, 0);                                                        \
        __builtin_amdgcn_global_load_lds(                                     \
            (const __attribute__((address_space(1))) void*)(Sf8 +             \
                (size_t)brow1 * GD + kof_ + akq1),                            \
            (__attribute__((address_space(3))) void*)&Bb[buf][base1][0],      \
            16, 0, 0);                                                        \
    } while (0)

    auto compute = [&](int buf) {
        i64x2 af[4], bfr[4];
        #pragma unroll
        for (int mi = 0; mi < 4; ++mi)
            af[mi] = *(const i64x2*)&Ab[buf][kb * 128 + wr * 64 + mi * 16 + r16][0];
        #pragma unroll
        for (int nj = 0; nj < 4; ++nj)
            bfr[nj] = *(const i64x2*)&Bb[buf][kb * 128 + wc * 64 + nj * 16 + r16][0];
        #pragma unroll
        for (int mi = 0; mi < 4; ++mi)
            #pragma unroll
            for (int nj = 0; nj < 4; ++nj) {
                acc[mi][nj] = __builtin_amdgcn_mfma_f32_16x16x32_fp8_fp8(
                    af[mi][0], bfr[nj][0], acc[mi][nj], 0, 0, 0);
                acc[mi][nj] = __builtin_amdgcn_mfma_f32_16x16x32_fp8_fp8(
                    af[mi][1], bfr[nj][1], acc[mi][nj], 0, 0, 0);
            }
    };

#define WAITVM_(N) asm volatile("s_waitcnt vmcnt(" #N ")" ::: "memory")
#define BARRIER()  asm volatile("s_barrier" ::: "memory")

#define KSTEP(ks, vm)                                                         \
    do {                                                                      \
        WAITVM_(vm);                                                          \
        BARRIER();                                                            \
        if ((ks) + 2 < 8) STAGE(((ks) + 2) % 3, (ks) + 2);                    \
        compute((ks) % 3);                                                    \
    } while (0)

    // prologue: 2 tiles in flight
    STAGE(0, 0);
    STAGE(1, 1);

    KSTEP(0, 4);   KSTEP(1, 4);   KSTEP(2, 4);   KSTEP(3, 4);
    KSTEP(4, 4);   KSTEP(5, 4);   KSTEP(6, 4);   KSTEP(7, 0);

#undef KSTEP
#undef WAITVM_
#undef BARRIER
#undef STAGE

    // ---- fused epilogue: fixed-shift partial softmax over 64-col wave tile
    const float w0 = wp[0], b0 = bp[0];
    const float C = fmaxf(w0 * 1e-6f + b0, w0 + b0);   // logit upper bound
    const int pcol = colp * 2 + wc;                    // 0..15 partial slot
    float isn[4];
    #pragma unroll
    for (int nj = 0; nj < 4; ++nj)
        isn[nj] = invSn[cbase + wc * 64 + nj * 16 + r16];

    #pragma unroll
    for (int mi = 0; mi < 4; ++mi) {
        #pragma unroll
        for (int r = 0; r < 4; ++r) {
            const int row = rbase + wr * 64 + mi * 16 + kb * 4 + r;
            const float ixn = invxn[row];
            const float cso = csown[row];
            const int own = row >> 5;
            float se = 0.f;
            #pragma unroll
            for (int nj = 0; nj < 4; ++nj) {
                const int col = cbase + wc * 64 + nj * 16 + r16;
                float cs = w0 * fmaxf(acc[mi][nj][r] * ixn * isn[nj], 1e-6f) + b0;
                cs = (col == own) ? cso : cs;
                se += __expf(cs - C);
            }
            #pragma unroll
            for (int off = 1; off < 16; off <<= 1)
                se += __shfl_xor(se, off, 16);
            if (r16 == 0)
                ps[(size_t)row * 16 + pcol] = se;
        }
    }
}

// ---------------------------------------------------------------------------
// Kernel C: combine 16 sum-partials per row (shared fixed shift C),
// loss = C + log(sum) - cs_own, mean-reduce into d_out[0].
// ---------------------------------------------------------------------------
__global__ __launch_bounds__(256) void finalize_kernel(
    const char* __restrict__ wsb, const float* __restrict__ wp,
    const float* __restrict__ bp, float* __restrict__ out)
{
    const float* csown = (const float*)(wsb + WS_CSOWN);
    const float* ps    = (const float*)(wsb + WS_PS);

    const float w0 = wp[0], b0 = bp[0];
    const float C = fmaxf(w0 * 1e-6f + b0, w0 + b0);

    const int row = blockIdx.x * 256 + threadIdx.x;
    float s = 0.f;
    #pragma unroll
    for (int i = 0; i < 16; ++i) s += ps[(size_t)row * 16 + i];
    float loss = C + logf(s) - csown[row];

    const int lane = threadIdx.x & 63;
    const int wid  = threadIdx.x >> 6;
    __shared__ float red[4];
    #pragma unroll
    for (int off = 32; off > 0; off >>= 1) loss += __shfl_down(loss, off);
    if (lane == 0) red[wid] = loss;
    __syncthreads();
    if (threadIdx.x == 0) {
        float sum = red[0] + red[1] + red[2] + red[3];
        atomicAdd(out, sum * (1.f / (GN * GM)));
    }
}

extern "C" void kernel_launch(void* const* d_in, const int* in_sizes, int n_in,
                              void* d_out, int out_size, void* d_ws, size_t ws_size,
                              hipStream_t stream)
{
    const float* x  = (const float*)d_in[0];
    const float* wp = (const float*)d_in[1];
    const float* bp = (const float*)d_in[2];
    float* out = (float*)d_out;
    char* wsb  = (char*)d_ws;

    hipMemsetAsync(d_out, 0, sizeof(float), stream);

    prep_kernel<<<GN, 512, 0, stream>>>(x, wp, bp, wsb);

    gemm_kernel<<<2048, 256, 0, stream>>>(wp, bp, wsb);

    finalize_kernel<<<128, 256, 0, stream>>>(wsb, wp, bp, out);
}

// Round 8
// 90.212 us; speedup vs baseline: 1.7890x; 1.1966x over previous
//
#include <hip/hip_runtime.h>
#include <hip/hip_bf16.h>
#include <hip/hip_fp8.h>
#include <math.h>

#define GN 1024
#define GM 32
#define GD 512
#define NROW (GN*GM)   // 32768

// ---------------- ws layout (bytes) ----------------
#define WS_XF8   0ull                  // u8 [NROW][512] = 16777216 (permuted fp8 image)
#define WS_SF8   16777216ull           // u8 [GN][512]   =   524288
#define WS_INVSN 17301504ull           // f32 [GN]
#define WS_INVXN 17305600ull           // f32 [NROW]
#define WS_CSOWN 17436672ull           // f32 [NROW]
#define WS_PS    17567744ull           // f32 [NROW*16]

typedef __attribute__((ext_vector_type(2))) long i64x2;
typedef __attribute__((ext_vector_type(4))) float f32x4;

__device__ inline unsigned char f32_to_e4m3(float f) {
    __hip_fp8_e4m3 q(f);               // OCP e4m3fn, saturating
    return (unsigned char)q.__x;
}

// fp8 image permutation within each row's 512 bytes:
// slot (ks, kb) 16B = [ksub0: k=ks*64+kb*8+j | ksub1: k=ks*64+32+kb*8+j]
// off(k) = (k & ~63) + ((k>>3)&3)*16 + ((k>>5)&1)*8 + (k&7)
__device__ inline int img_off(int k) {
    const int rem = k & 63;
    return (k & ~63) + ((rem >> 3) & 3) * 16 + (rem >> 5) * 8 + (rem & 7);
}

// ---------------------------------------------------------------------------
// Kernel A: per speaker n — centroid sums, norms, own-centroid cosine,
// plus permuted-fp8 conversion of x and S. x read from HBM ONCE; staged in
// LDS (f32, 64 KB) for the phase-2 per-utterance reductions.
// grid GN blocks, 512 threads.
// ---------------------------------------------------------------------------
__global__ __launch_bounds__(512) void prep_kernel(
    const float* __restrict__ x, const float* __restrict__ wp,
    const float* __restrict__ bp, char* __restrict__ wsb)
{
    unsigned char* xf8 = (unsigned char*)(wsb + WS_XF8);
    unsigned char* Sf8 = (unsigned char*)(wsb + WS_SF8);
    float* invSn = (float*)(wsb + WS_INVSN);
    float* invxn = (float*)(wsb + WS_INVXN);
    float* csown = (float*)(wsb + WS_CSOWN);

    const int n = blockIdx.x;
    const int d = threadIdx.x;           // 0..511 (= k index)
    const int lane = d & 63;
    const int wid  = d >> 6;             // 0..7

    __shared__ float sx[GM][GD];         // 64 KB: x panel, f32
    __shared__ float sS[GD];
    __shared__ float red[8];
    __shared__ float sSn2;

    const float* xn_ = x + (size_t)n * GM * GD;
    const int off = img_off(d);

    // phase 1: single global read of x; stage to LDS; column sum; fp8 image
    float Sd = 0.f;
    #pragma unroll
    for (int m = 0; m < GM; ++m) {
        float xv = xn_[m * GD + d];
        sx[m][d] = xv;
        Sd += xv;
        xf8[(size_t)(n * GM + m) * GD + off] = f32_to_e4m3(xv);
    }
    sS[d] = Sd;
    Sf8[(size_t)n * GD + off] = f32_to_e4m3(Sd);

    // ||S||^2
    float p = Sd * Sd;
    #pragma unroll
    for (int o = 32; o > 0; o >>= 1) p += __shfl_down(p, o);
    if (lane == 0) red[wid] = p;
    __syncthreads();
    if (d == 0) {
        float s = 0.f;
        #pragma unroll
        for (int i = 0; i < 8; ++i) s += red[i];
        sSn2 = s;
        invSn[n] = rsqrtf(s);
    }
    __syncthreads();

    // phase 2: per-utterance norms + dot(x, S) from LDS
    const float w0 = wp[0], b0 = bp[0];
    const float Sn2 = sSn2;
    #pragma unroll
    for (int mm = 0; mm < 4; ++mm) {
        const int m = wid + mm * 8;
        float xn2 = 0.f, dn = 0.f;
        #pragma unroll
        for (int j = 0; j < 8; ++j) {
            float xv = sx[m][lane + 64 * j];
            float sv = sS[lane + 64 * j];
            xn2 += xv * xv;
            dn  += xv * sv;
        }
        #pragma unroll
        for (int o = 32; o > 0; o >>= 1) {
            xn2 += __shfl_down(xn2, o);
            dn  += __shfl_down(dn, o);
        }
        if (lane == 0) {
            float ixn = rsqrtf(xn2);
            float en2 = Sn2 - 2.f * dn + xn2;          // ||S - x||^2
            float cosown = (dn - xn2) * ixn * rsqrtf(en2);
            csown[n * GM + m] = w0 * fmaxf(cosown, 1e-6f) + b0;
            invxn[n * GM + m] = ixn;
        }
    }
}

// ---------------------------------------------------------------------------
// Kernel B: fp8 MFMA GEMM G = x(32768x512) * S^T(512x1024), e4m3 inputs.
// 256x128 block / BK=64 / 4 waves (2x2), each wave 128x64 (8x4 fragments,
// 2 k-sub MFMAs each) -> LDS-read/FLOP ratio 85 vs 64 for 64x64 waves.
// 3 LDS buffers (72 KB -> 2 blocks/CU), prefetch distance 2, ONE raw
// s_barrier per K-step, counted vmcnt(6). 8 K-steps. XCD-aware bid
// swizzle. Fused fixed-shift partial-softmax epilogue.
// grid 1024 blocks, 256 threads.
// ---------------------------------------------------------------------------
__global__ __launch_bounds__(256, 2) void gemm_kernel(
    const float* __restrict__ wp, const float* __restrict__ bp,
    char* __restrict__ wsb)
{
    const unsigned char* xf8 = (const unsigned char*)(wsb + WS_XF8);
    const unsigned char* Sf8 = (const unsigned char*)(wsb + WS_SF8);
    const float* invSn = (const float*)(wsb + WS_INVSN);
    const float* invxn = (const float*)(wsb + WS_INVXN);
    const float* csown = (const float*)(wsb + WS_CSOWN);
    float* ps = (float*)(wsb + WS_PS);

    // A slot s = kb*256 + row (kb 0..3, row 0..255); B slot = kb*128 + row
    __shared__ __align__(16) unsigned char Ab[3][1024][16];   // 48 KB
    __shared__ __align__(16) unsigned char Bb[3][512][16];    // 24 KB

    // XCD swizzle: hw xcd = bid & 7 owns row-panels [xcd*16, xcd*16+16)
    const int bid  = blockIdx.x;          // 0..1023
    const int u    = bid >> 3;            // 0..127
    const int rowp = (bid & 7) * 16 + (u >> 3);
    const int colp = u & 7;
    const int rbase = rowp * 256;
    const int cbase = colp * 128;

    const int t    = threadIdx.x;
    const int w    = t >> 6;
    const int lane = t & 63;
    const int wr   = w >> 1, wc = w & 1;   // wave tile: rows wr*128, cols wc*64

    const int kb  = lane >> 4;   // k-chunk 0..3 (also C row-group)
    const int r16 = lane & 15;

    f32x4 acc[8][4] = {};

    // Staging: thread t owns A row (rbase+t), all 4 kb-chunks (p=0..3,
    // slot p*256+t -> kb=p,row=t), and 2 B chunks (p=0..1, slot p*256+t
    // -> kb=p*2+(t>>7), row=t&127).
    const unsigned char* agbase = xf8 + (size_t)(rbase + t) * GD;
    const unsigned char* bgbase = Sf8 + (size_t)(cbase + (t & 127)) * GD + (t >> 7) * 16;
    // wave-uniform LDS slot bases (HW adds lane*16B)
    const int wbase = w * 64;

#define STAGE(buf, ks)                                                        \
    do {                                                                      \
        const int kof_ = (ks) * 64;                                           \
        __builtin_amdgcn_global_load_lds(                                     \
            (const __attribute__((address_space(1))) void*)(agbase + kof_),   \
            (__attribute__((address_space(3))) void*)&Ab[buf][wbase][0],      \
            16, 0, 0);                                                        \
        __builtin_amdgcn_global_load_lds(                                     \
            (const __attribute__((address_space(1))) void*)(agbase + kof_ + 16), \
            (__attribute__((address_space(3))) void*)&Ab[buf][256 + wbase][0],\
            16, 0, 0);                                                        \
        __builtin_amdgcn_global_load_lds(                                     \
            (const __attribute__((address_space(1))) void*)(agbase + kof_ + 32), \
            (__attribute__((address_space(3))) void*)&Ab[buf][512 + wbase][0],\
            16, 0, 0);                                                        \
        __builtin_amdgcn_global_load_lds(                                     \
            (const __attribute__((address_space(1))) void*)(agbase + kof_ + 48), \
            (__attribute__((address_space(3))) void*)&Ab[buf][768 + wbase][0],\
            16, 0, 0);                                                        \
        __builtin_amdgcn_global_load_lds(                                     \
            (const __attribute__((address_space(1))) void*)(bgbase + kof_),   \
            (__attribute__((address_space(3))) void*)&Bb[buf][wbase][0],      \
            16, 0, 0);                                                        \
        __builtin_amdgcn_global_load_lds(                                     \
            (const __attribute__((address_space(1))) void*)(bgbase + kof_ + 32), \
            (__attribute__((address_space(3))) void*)&Bb[buf][256 + wbase][0],\
            16, 0, 0);                                                        \
    } while (0)

    auto compute = [&](int buf) {
        i64x2 af[8], bfr[4];
        #pragma unroll
        for (int mi = 0; mi < 8; ++mi)
            af[mi] = *(const i64x2*)&Ab[buf][kb * 256 + wr * 128 + mi * 16 + r16][0];
        #pragma unroll
        for (int nj = 0; nj < 4; ++nj)
            bfr[nj] = *(const i64x2*)&Bb[buf][kb * 128 + wc * 64 + nj * 16 + r16][0];
        #pragma unroll
        for (int mi = 0; mi < 8; ++mi)
            #pragma unroll
            for (int nj = 0; nj < 4; ++nj) {
                acc[mi][nj] = __builtin_amdgcn_mfma_f32_16x16x32_fp8_fp8(
                    af[mi][0], bfr[nj][0], acc[mi][nj], 0, 0, 0);
                acc[mi][nj] = __builtin_amdgcn_mfma_f32_16x16x32_fp8_fp8(
                    af[mi][1], bfr[nj][1], acc[mi][nj], 0, 0, 0);
            }
    };

#define WAITVM_(N) asm volatile("s_waitcnt vmcnt(" #N ")" ::: "memory")
#define BARRIER()  asm volatile("s_barrier" ::: "memory")

#define KSTEP(ks, vm)                                                         \
    do {                                                                      \
        WAITVM_(vm);                                                          \
        BARRIER();                                                            \
        if ((ks) + 2 < 8) STAGE(((ks) + 2) % 3, (ks) + 2);                    \
        compute((ks) % 3);                                                    \
    } while (0)

    // prologue: 2 tiles in flight (12 loads)
    STAGE(0, 0);
    STAGE(1, 1);

    KSTEP(0, 6);   KSTEP(1, 6);   KSTEP(2, 6);   KSTEP(3, 6);
    KSTEP(4, 6);   KSTEP(5, 6);   KSTEP(6, 6);   KSTEP(7, 0);

#undef KSTEP
#undef WAITVM_
#undef BARRIER
#undef STAGE

    // ---- fused epilogue: fixed-shift partial softmax over 64-col wave tile
    const float w0 = wp[0], b0 = bp[0];
    const float C = fmaxf(w0 * 1e-6f + b0, w0 + b0);   // logit upper bound
    const int pcol = colp * 2 + wc;                    // 0..15 partial slot
    float isn[4];
    #pragma unroll
    for (int nj = 0; nj < 4; ++nj)
        isn[nj] = invSn[cbase + wc * 64 + nj * 16 + r16];

    #pragma unroll
    for (int mi = 0; mi < 8; ++mi) {
        #pragma unroll
        for (int r = 0; r < 4; ++r) {
            const int row = rbase + wr * 128 + mi * 16 + kb * 4 + r;
            const float ixn = invxn[row];
            const float cso = csown[row];
            const int own = row >> 5;
            float se = 0.f;
            #pragma unroll
            for (int nj = 0; nj < 4; ++nj) {
                const int col = cbase + wc * 64 + nj * 16 + r16;
                float cs = w0 * fmaxf(acc[mi][nj][r] * ixn * isn[nj], 1e-6f) + b0;
                cs = (col == own) ? cso : cs;
                se += __expf(cs - C);
            }
            #pragma unroll
            for (int off = 1; off < 16; off <<= 1)
                se += __shfl_xor(se, off, 16);
            if (r16 == 0)
                ps[(size_t)row * 16 + pcol] = se;
        }
    }
}

// ---------------------------------------------------------------------------
// Kernel C: combine 16 sum-partials per row (shared fixed shift C),
// loss = C + log(sum) - cs_own, mean-reduce into d_out[0].
// ---------------------------------------------------------------------------
__global__ __launch_bounds__(256) void finalize_kernel(
    const char* __restrict__ wsb, const float* __restrict__ wp,
    const float* __restrict__ bp, float* __restrict__ out)
{
    const float* csown = (const float*)(wsb + WS_CSOWN);
    const float* ps    = (const float*)(wsb + WS_PS);

    const float w0 = wp[0], b0 = bp[0];
    const float C = fmaxf(w0 * 1e-6f + b0, w0 + b0);

    const int row = blockIdx.x * 256 + threadIdx.x;
    float s = 0.f;
    #pragma unroll
    for (int i = 0; i < 16; ++i) s += ps[(size_t)row * 16 + i];
    float loss = C + logf(s) - csown[row];

    const int lane = threadIdx.x & 63;
    const int wid  = threadIdx.x >> 6;
    __shared__ float red[4];
    #pragma unroll
    for (int off = 32; off > 0; off >>= 1) loss += __shfl_down(loss, off);
    if (lane == 0) red[wid] = loss;
    __syncthreads();
    if (threadIdx.x == 0) {
        float sum = red[0] + red[1] + red[2] + red[3];
        atomicAdd(out, sum * (1.f / (GN * GM)));
    }
}

extern "C" void kernel_launch(void* const* d_in, const int* in_sizes, int n_in,
                              void* d_out, int out_size, void* d_ws, size_t ws_size,
                              hipStream_t stream)
{
    const float* x  = (const float*)d_in[0];
    const float* wp = (const float*)d_in[1];
    const float* bp = (const float*)d_in[2];
    float* out = (float*)d_out;
    char* wsb  = (char*)d_ws;

    hipMemsetAsync(d_out, 0, sizeof(float), stream);

    prep_kernel<<<GN, 512, 0, stream>>>(x, wp, bp, wsb);

    gemm_kernel<<<1024, 256, 0, stream>>>(wp, bp, wsb);

    finalize_kernel<<<128, 256, 0, stream>>>(wsb, wp, bp, out);
}

// Round 9
// 82.653 us; speedup vs baseline: 1.9526x; 1.0915x over previous
//
#include <hip/hip_runtime.h>
#include <hip/hip_bf16.h>
#include <hip/hip_fp8.h>
#include <math.h>

#define GN 1024
#define GM 32
#define GD 512
#define NROW (GN*GM)   // 32768

// ---------------- ws layout (bytes) ----------------
#define WS_XF8   0ull                  // u8 [NROW][512] = 16777216 (permuted fp8 image)
#define WS_SF8   16777216ull           // u8 [GN][512]   =   524288
#define WS_INVSN 17301504ull           // f32 [GN]
#define WS_INVXN 17305600ull           // f32 [NROW]
#define WS_CSOWN 17436672ull           // f32 [NROW]
#define WS_PS    17567744ull           // f32 [NROW*16]

typedef __attribute__((ext_vector_type(2))) long i64x2;
typedef __attribute__((ext_vector_type(4))) float f32x4;

__device__ inline unsigned char f32_to_e4m3(float f) {
    __hip_fp8_e4m3 q(f);               // OCP e4m3fn, saturating
    return (unsigned char)q.__x;
}

// fp8 image permutation within each row's 512 bytes:
// slot (ks, kb) 16B = [ksub0: k=ks*64+kb*8+j | ksub1: k=ks*64+32+kb*8+j]
// off(k) = (k & ~63) + ((k>>3)&3)*16 + ((k>>5)&1)*8 + (k&7)
__device__ inline int img_off(int k) {
    const int rem = k & 63;
    return (k & ~63) + ((rem >> 3) & 3) * 16 + (rem >> 5) * 8 + (rem & 7);
}

// ---------------------------------------------------------------------------
// Kernel A: per speaker n — centroid sums, norms, own-centroid cosine,
// plus permuted-fp8 conversion of x and S. x read from HBM ONCE; staged in
// LDS (f32, 64 KB) for the phase-2 per-utterance reductions.
// grid GN blocks, 512 threads.
// ---------------------------------------------------------------------------
__global__ __launch_bounds__(512) void prep_kernel(
    const float* __restrict__ x, const float* __restrict__ wp,
    const float* __restrict__ bp, char* __restrict__ wsb)
{
    unsigned char* xf8 = (unsigned char*)(wsb + WS_XF8);
    unsigned char* Sf8 = (unsigned char*)(wsb + WS_SF8);
    float* invSn = (float*)(wsb + WS_INVSN);
    float* invxn = (float*)(wsb + WS_INVXN);
    float* csown = (float*)(wsb + WS_CSOWN);

    const int n = blockIdx.x;
    const int d = threadIdx.x;           // 0..511 (= k index)
    const int lane = d & 63;
    const int wid  = d >> 6;             // 0..7

    __shared__ float sx[GM][GD];         // 64 KB: x panel, f32
    __shared__ float sS[GD];
    __shared__ float red[8];
    __shared__ float sSn2;

    const float* xn_ = x + (size_t)n * GM * GD;
    const int off = img_off(d);

    // phase 1: single global read of x; stage to LDS; column sum; fp8 image
    float Sd = 0.f;
    #pragma unroll
    for (int m = 0; m < GM; ++m) {
        float xv = xn_[m * GD + d];
        sx[m][d] = xv;
        Sd += xv;
        xf8[(size_t)(n * GM + m) * GD + off] = f32_to_e4m3(xv);
    }
    sS[d] = Sd;
    Sf8[(size_t)n * GD + off] = f32_to_e4m3(Sd);

    // ||S||^2
    float p = Sd * Sd;
    #pragma unroll
    for (int o = 32; o > 0; o >>= 1) p += __shfl_down(p, o);
    if (lane == 0) red[wid] = p;
    __syncthreads();
    if (d == 0) {
        float s = 0.f;
        #pragma unroll
        for (int i = 0; i < 8; ++i) s += red[i];
        sSn2 = s;
        invSn[n] = rsqrtf(s);
    }
    __syncthreads();

    // phase 2: per-utterance norms + dot(x, S) from LDS
    const float w0 = wp[0], b0 = bp[0];
    const float Sn2 = sSn2;
    #pragma unroll
    for (int mm = 0; mm < 4; ++mm) {
        const int m = wid + mm * 8;
        float xn2 = 0.f, dn = 0.f;
        #pragma unroll
        for (int j = 0; j < 8; ++j) {
            float xv = sx[m][lane + 64 * j];
            float sv = sS[lane + 64 * j];
            xn2 += xv * xv;
            dn  += xv * sv;
        }
        #pragma unroll
        for (int o = 32; o > 0; o >>= 1) {
            xn2 += __shfl_down(xn2, o);
            dn  += __shfl_down(dn, o);
        }
        if (lane == 0) {
            float ixn = rsqrtf(xn2);
            float en2 = Sn2 - 2.f * dn + xn2;          // ||S - x||^2
            float cosown = (dn - xn2) * ixn * rsqrtf(en2);
            csown[n * GM + m] = w0 * fmaxf(cosown, 1e-6f) + b0;
            invxn[n * GM + m] = ixn;
        }
    }
}

// ---------------------------------------------------------------------------
// Kernel B: fp8 MFMA GEMM G = x(32768x512) * S^T(512x1024), e4m3 inputs.
// 128x128 tile / BK=64 / 4 waves (2x2) / 4x4 fragments, 2 k-sub MFMAs per
// ds_read_b128. 2 LDS buffers (32 KB -> 5 blocks/CU = 20 waves): occupancy
// over schedule depth. Per step: vmcnt(0) drain + ONE raw s_barrier, then
// STAGE(next) issued BEFORE compute so its latency hides under the MFMAs
// and the 4 other co-resident blocks. 8 K-steps. XCD-aware bid swizzle.
// Fused fixed-shift partial-softmax epilogue. grid 2048 blocks, 256 thr.
// ---------------------------------------------------------------------------
__global__ __launch_bounds__(256) void gemm_kernel(
    const float* __restrict__ wp, const float* __restrict__ bp,
    char* __restrict__ wsb)
{
    const unsigned char* xf8 = (const unsigned char*)(wsb + WS_XF8);
    const unsigned char* Sf8 = (const unsigned char*)(wsb + WS_SF8);
    const float* invSn = (const float*)(wsb + WS_INVSN);
    const float* invxn = (const float*)(wsb + WS_INVXN);
    const float* csown = (const float*)(wsb + WS_CSOWN);
    float* ps = (float*)(wsb + WS_PS);

    // slot s = kb*128 + row; 16 B = both k-subs of (row, kb) for this step
    __shared__ __align__(16) unsigned char Ab[2][512][16];   // 16 KB
    __shared__ __align__(16) unsigned char Bb[2][512][16];   // 16 KB

    // XCD swizzle: hw xcd = bid & 7 owns row-panels [xcd*32, xcd*32+32)
    const int bid  = blockIdx.x;          // 0..2047
    const int u    = bid >> 3;            // 0..255
    const int rowp = (bid & 7) * 32 + (u >> 3);
    const int colp = u & 7;
    const int rbase = rowp * 128;
    const int cbase = colp * 128;

    const int t    = threadIdx.x;
    const int w    = t >> 6;
    const int lane = t & 63;
    const int wr   = w >> 1, wc = w & 1;

    const int kb  = lane >> 4;   // k-chunk 0..3 (also C row-group)
    const int r16 = lane & 15;

    f32x4 acc[4][4] = {};

    // staging slots for this thread: s = p*256 + t, p = 0..1
    const int s0 = t, s1 = 256 + t;
    const int arow0 = rbase + (s0 & 127), akq0 = (s0 >> 7) * 16;
    const int arow1 = rbase + (s1 & 127), akq1 = (s1 >> 7) * 16;
    const int brow0 = cbase + (s0 & 127);
    const int brow1 = cbase + (s1 & 127);
    // wave-uniform LDS slot bases (HW adds lane*16B)
    const int base0 = (t >> 6) * 64;          // slots   0..255 region
    const int base1 = 256 + (t >> 6) * 64;    // slots 256..511 region

#define STAGE(buf, ks)                                                        \
    do {                                                                      \
        const int kof_ = (ks) * 64;                                           \
        __builtin_amdgcn_global_load_lds(                                     \
            (const __attribute__((address_space(1))) void*)(xf8 +             \
                (size_t)arow0 * GD + kof_ + akq0),                            \
            (__attribute__((address_space(3))) void*)&Ab[buf][base0][0],      \
            16, 0, 0);                                                        \
        __builtin_amdgcn_global_load_lds(                                     \
            (const __attribute__((address_space(1))) void*)(xf8 +             \
                (size_t)arow1 * GD + kof_ + akq1),                            \
            (__attribute__((address_space(3))) void*)&Ab[buf][base1][0],      \
            16, 0, 0);                                                        \
        __builtin_amdgcn_global_load_lds(                                     \
            (const __attribute__((address_space(1))) void*)(Sf8 +             \
                (size_t)brow0 * GD + kof_ + akq0),                            \
            (__attribute__((address_space(3))) void*)&Bb[buf][base0][0],      \
            16, 0, 0);                                                        \
        __builtin_amdgcn_global_load_lds(                                     \
            (const __attribute__((address_space(1))) void*)(Sf8 +             \
                (size_t)brow1 * GD + kof_ + akq1),                            \
            (__attribute__((address_space(3))) void*)&Bb[buf][base1][0],      \
            16, 0, 0);                                                        \
    } while (0)

    auto compute = [&](int buf) {
        i64x2 af[4], bfr[4];
        #pragma unroll
        for (int mi = 0; mi < 4; ++mi)
            af[mi] = *(const i64x2*)&Ab[buf][kb * 128 + wr * 64 + mi * 16 + r16][0];
        #pragma unroll
        for (int nj = 0; nj < 4; ++nj)
            bfr[nj] = *(const i64x2*)&Bb[buf][kb * 128 + wc * 64 + nj * 16 + r16][0];
        #pragma unroll
        for (int mi = 0; mi < 4; ++mi)
            #pragma unroll
            for (int nj = 0; nj < 4; ++nj) {
                acc[mi][nj] = __builtin_amdgcn_mfma_f32_16x16x32_fp8_fp8(
                    af[mi][0], bfr[nj][0], acc[mi][nj], 0, 0, 0);
                acc[mi][nj] = __builtin_amdgcn_mfma_f32_16x16x32_fp8_fp8(
                    af[mi][1], bfr[nj][1], acc[mi][nj], 0, 0, 0);
            }
    };

#define WAITVM0()  asm volatile("s_waitcnt vmcnt(0)" ::: "memory")
#define BARRIER()  asm volatile("s_barrier" ::: "memory")

    // Step ks: drain tile ks (own loads), barrier (=> everyone's tile ks in
    // LDS; everyone done issuing step ks-1 reads), stage tile ks+1 into the
    // buffer last read at step ks-1, compute tile ks.
#define KSTEP(ks)                                                             \
    do {                                                                      \
        WAITVM0();                                                            \
        BARRIER();                                                            \
        if ((ks) + 1 < 8) STAGE(((ks) + 1) & 1, (ks) + 1);                    \
        compute((ks) & 1);                                                    \
    } while (0)

    // prologue: 1 tile in flight
    STAGE(0, 0);

    KSTEP(0);  KSTEP(1);  KSTEP(2);  KSTEP(3);
    KSTEP(4);  KSTEP(5);  KSTEP(6);  KSTEP(7);

#undef KSTEP
#undef WAITVM0
#undef BARRIER
#undef STAGE

    // ---- fused epilogue: fixed-shift partial softmax over 64-col wave tile
    const float w0 = wp[0], b0 = bp[0];
    const float C = fmaxf(w0 * 1e-6f + b0, w0 + b0);   // logit upper bound
    const int pcol = colp * 2 + wc;                    // 0..15 partial slot
    float isn[4];
    #pragma unroll
    for (int nj = 0; nj < 4; ++nj)
        isn[nj] = invSn[cbase + wc * 64 + nj * 16 + r16];

    #pragma unroll
    for (int mi = 0; mi < 4; ++mi) {
        #pragma unroll
        for (int r = 0; r < 4; ++r) {
            const int row = rbase + wr * 64 + mi * 16 + kb * 4 + r;
            const float ixn = invxn[row];
            const float cso = csown[row];
            const int own = row >> 5;
            float se = 0.f;
            #pragma unroll
            for (int nj = 0; nj < 4; ++nj) {
                const int col = cbase + wc * 64 + nj * 16 + r16;
                float cs = w0 * fmaxf(acc[mi][nj][r] * ixn * isn[nj], 1e-6f) + b0;
                cs = (col == own) ? cso : cs;
                se += __expf(cs - C);
            }
            #pragma unroll
            for (int off = 1; off < 16; off <<= 1)
                se += __shfl_xor(se, off, 16);
            if (r16 == 0)
                ps[(size_t)row * 16 + pcol] = se;
        }
    }
}

// ---------------------------------------------------------------------------
// Kernel C: combine 16 sum-partials per row (shared fixed shift C),
// loss = C + log(sum) - cs_own, mean-reduce into d_out[0].
// ---------------------------------------------------------------------------
__global__ __launch_bounds__(256) void finalize_kernel(
    const char* __restrict__ wsb, const float* __restrict__ wp,
    const float* __restrict__ bp, float* __restrict__ out)
{
    const float* csown = (const float*)(wsb + WS_CSOWN);
    const float* ps    = (const float*)(wsb + WS_PS);

    const float w0 = wp[0], b0 = bp[0];
    const float C = fmaxf(w0 * 1e-6f + b0, w0 + b0);

    const int row = blockIdx.x * 256 + threadIdx.x;
    float s = 0.f;
    #pragma unroll
    for (int i = 0; i < 16; ++i) s += ps[(size_t)row * 16 + i];
    float loss = C + logf(s) - csown[row];

    const int lane = threadIdx.x & 63;
    const int wid  = threadIdx.x >> 6;
    __shared__ float red[4];
    #pragma unroll
    for (int off = 32; off > 0; off >>= 1) loss += __shfl_down(loss, off);
    if (lane == 0) red[wid] = loss;
    __syncthreads();
    if (threadIdx.x == 0) {
        float sum = red[0] + red[1] + red[2] + red[3];
        atomicAdd(out, sum * (1.f / (GN * GM)));
    }
}

extern "C" void kernel_launch(void* const* d_in, const int* in_sizes, int n_in,
                              void* d_out, int out_size, void* d_ws, size_t ws_size,
                              hipStream_t stream)
{
    const float* x  = (const float*)d_in[0];
    const float* wp = (const float*)d_in[1];
    const float* bp = (const float*)d_in[2];
    float* out = (float*)d_out;
    char* wsb  = (char*)d_ws;

    hipMemsetAsync(d_out, 0, sizeof(float), stream);

    prep_kernel<<<GN, 512, 0, stream>>>(x, wp, bp, wsb);

    gemm_kernel<<<2048, 256, 0, stream>>>(wp, bp, wsb);

    finalize_kernel<<<128, 256, 0, stream>>>(wsb, wp, bp, out);
}